// Round 1
// baseline (68.778 us; speedup 1.0000x reference)
//
#include <hip/hip_runtime.h>

// SpanMaskGenerator: B=256, S=131072, 4 spans/batch.
// Outputs (concatenated int32): context_mask [B,S], target_mask [B,S],
// padded_positions [B,S] (masked positions ascending, sentinel = S).
//
// Union of 4 start-sorted spans = <=4 disjoint ascending segments
// [max(ss[i],M_{i-1}), max(ee[i],M_{i-1})) with M = running max of ends.
// padded_positions is a closed-form per-index lookup -> pure streaming map,
// no sort, no scatter, fully coalesced int4 stores.

constexpr int S_LEN = 131072;
constexpr int NBLK  = 4;
constexpr int TPB   = 256;
constexpr int ITEMS = 8;

__global__ __launch_bounds__(TPB) void span_mask_kernel(
    const float* __restrict__ scales_u,
    const float* __restrict__ starts_u,
    int* __restrict__ out,
    int batch)
{
    const int b = blockIdx.y;

    // ---- per-batch span computation (uniform across all threads; cheap) ----
    // Exact f32 replication of the reference: separate mul/add (no fma
    // contraction), truncating int casts.
    int ss[NBLK], ee[NBLK];
#pragma unroll
    for (int t = 0; t < NBLK; ++t) {
        float u  = scales_u[b * NBLK + t];
        float r  = starts_u[b * NBLK + t];
        float sc = __fadd_rn(0.15f, __fmul_rn(u, 0.05f));      // U(0.15,0.2)
        int len  = (int)__fmul_rn(sc, 131072.0f);              // trunc
        if (len < 1) len = 1;
        int mx   = S_LEN - len; if (mx < 0) mx = 0;
        int st   = (int)__fmul_rn(r, __fadd_rn((float)mx, 1.0f)); // trunc
        int en   = st + len; if (en > S_LEN) en = S_LEN;
        ss[t] = st; ee[t] = en;
    }

    // ---- sort 4 spans by start (sorting network, static indices only) ----
#define CSWAP(i, j)                                                        \
    if (ss[i] > ss[j]) {                                                   \
        int t0 = ss[i]; ss[i] = ss[j]; ss[j] = t0;                         \
        int t1 = ee[i]; ee[i] = ee[j]; ee[j] = t1;                         \
    }
    CSWAP(0, 1) CSWAP(2, 3) CSWAP(0, 2) CSWAP(1, 3) CSWAP(1, 2)
#undef CSWAP

    // ---- marginal-contribution segments (disjoint, ascending) ----
    const int L0 = ss[0],          R0 = ee[0];
    const int L1 = max(ss[1], R0), R1 = max(ee[1], R0);
    const int L2 = max(ss[2], R1), R2 = max(ee[2], R1);
    const int L3 = max(ss[3], R2), R3 = max(ee[3], R2);
    const int c1 = R0 - L0;                 // cumulative masked counts
    const int c2 = c1 + (R1 - L1);
    const int c3 = c2 + (R2 - L2);
    const int total = c3 + (R3 - L3);

    const size_t BS   = (size_t)batch * S_LEN;
    const size_t base = (size_t)b * S_LEN;
    int* __restrict__ ctx = out + base;            // context_mask
    int* __restrict__ tgt = out + BS + base;       // target_mask
    int* __restrict__ pad = out + 2 * BS + base;   // padded_positions

    const int p0 = (blockIdx.x * TPB + threadIdx.x) * ITEMS;

    int tv[ITEMS], cv[ITEMS], pv[ITEMS];
#pragma unroll
    for (int i = 0; i < ITEMS; ++i) {
        const int s = p0 + i;
        const int cov =
            ((s >= ss[0]) & (s < ee[0])) | ((s >= ss[1]) & (s < ee[1])) |
            ((s >= ss[2]) & (s < ee[2])) | ((s >= ss[3]) & (s < ee[3]));
        tv[i] = cov;
        cv[i] = cov ^ 1;
        // padded_positions[k]: k-th masked position, else sentinel S_LEN.
        // Empty segments have zero width in the cumulative brackets, so the
        // select chain skips them naturally.
        int v;
        if      (s >= total) v = S_LEN;
        else if (s >= c3)    v = L3 + (s - c3);
        else if (s >= c2)    v = L2 + (s - c2);
        else if (s >= c1)    v = L1 + (s - c1);
        else                 v = L0 + s;
        pv[i] = v;
    }

    reinterpret_cast<int4*>(ctx + p0)[0] = make_int4(cv[0], cv[1], cv[2], cv[3]);
    reinterpret_cast<int4*>(ctx + p0)[1] = make_int4(cv[4], cv[5], cv[6], cv[7]);
    reinterpret_cast<int4*>(tgt + p0)[0] = make_int4(tv[0], tv[1], tv[2], tv[3]);
    reinterpret_cast<int4*>(tgt + p0)[1] = make_int4(tv[4], tv[5], tv[6], tv[7]);
    reinterpret_cast<int4*>(pad + p0)[0] = make_int4(pv[0], pv[1], pv[2], pv[3]);
    reinterpret_cast<int4*>(pad + p0)[1] = make_int4(pv[4], pv[5], pv[6], pv[7]);
}

extern "C" void kernel_launch(void* const* d_in, const int* in_sizes, int n_in,
                              void* d_out, int out_size, void* d_ws, size_t ws_size,
                              hipStream_t stream)
{
    const float* scales_u = (const float*)d_in[0];
    const float* starts_u = (const float*)d_in[1];
    // d_in[2]/d_in[3] are batch_size=256 / seq_len=131072 scalars (fixed).
    const int batch = 256;
    dim3 grid(S_LEN / (TPB * ITEMS), batch);   // (64, 256)
    span_mask_kernel<<<grid, dim3(TPB), 0, stream>>>(
        scales_u, starts_u, (int*)d_out, batch);
}